// Round 1
// baseline (1194.590 us; speedup 1.0000x reference)
//
#include <hip/hip_runtime.h>
#include <hip/hip_bf16.h>

typedef unsigned short u16;
typedef float f32x4 __attribute__((ext_vector_type(4)));
typedef short s16x8 __attribute__((ext_vector_type(8)));

__device__ __forceinline__ float b2f(u16 u) {
    unsigned int x = ((unsigned int)u) << 16;
    return __builtin_bit_cast(float, x);
}
__device__ __forceinline__ u16 f2b(float f) {
    unsigned int x = __builtin_bit_cast(unsigned int, f);
    unsigned int lsb = (x >> 16) & 1u;
    x += 0x7fffu + lsb;                 // RNE; inputs are finite
    return (u16)(x >> 16);
}

#define GLOAD_LDS(g, l) __builtin_amdgcn_global_load_lds( \
    (const __attribute__((address_space(1))) void*)(g),   \
    (__attribute__((address_space(3))) void*)(l), 16, 0, 0)

// ---------------------------------------------------------------------------
// Generic batched GEMM: C[z,m,n] = sum_k A[z,m,k] * B[z,n,k]   (B is [N][K])
// Tile 128x128, BK=32, 256 threads = 4 waves (2x2), mfma_f32_16x16x32_bf16.
// EPI: 0 Cf=acc   1 Cf+=acc   2 Cb=relu(acc+Cf+bias)   3 Cb=relu(acc+bias)*mask
//      4 Cb=acc*mask[row]*mask[col]   5 Cb=acc   6 Cb=2*acc - prev2
// ---------------------------------------------------------------------------
template<int EPI>
__global__ __launch_bounds__(256)
void gemm_bt(const u16* __restrict__ A, const u16* __restrict__ B,
             float* __restrict__ Cf, u16* __restrict__ Cb,
             const float* __restrict__ bias, int biasBStride,
             const float* __restrict__ mask, const u16* __restrict__ prev2,
             int M, int N, int K, int lda, int ldb, int ldc,
             long aBS, long bBS, long cBS)
{
    __shared__ u16 As[128 * 32];
    __shared__ u16 Bs[128 * 32];
    const int tid  = threadIdx.x;
    const int lane = tid & 63;
    const int z    = blockIdx.z;
    const int m0   = blockIdx.y * 128;
    const int n0   = blockIdx.x * 128;
    const int wm   = ((tid >> 7) & 1) * 64;
    const int wn   = ((tid >> 6) & 1) * 64;
    const int l15  = lane & 15;
    const int lg   = lane >> 4;
    const u16* Ab = A + (long)z * aBS;
    const u16* Bb = B + (long)z * bBS;

    f32x4 acc[4][4] = {};

    const int u0 = tid, u1 = tid + 256;
    for (int t = 0; t < K; t += 32) {
        const u16* ga0 = Ab + (long)(m0 + (u0 >> 2)) * lda + t + (u0 & 3) * 8;
        const u16* ga1 = Ab + (long)(m0 + (u1 >> 2)) * lda + t + (u1 & 3) * 8;
        const u16* gb0 = Bb + (long)(n0 + (u0 >> 2)) * ldb + t + (u0 & 3) * 8;
        const u16* gb1 = Bb + (long)(n0 + (u1 >> 2)) * ldb + t + (u1 & 3) * 8;
        GLOAD_LDS(ga0, &As[u0 * 8]);
        GLOAD_LDS(ga1, &As[u1 * 8]);
        GLOAD_LDS(gb0, &Bs[u0 * 8]);
        GLOAD_LDS(gb1, &Bs[u1 * 8]);
        __syncthreads();
        s16x8 af[4], bg[4];
        #pragma unroll
        for (int i = 0; i < 4; ++i) {
            af[i] = *(const s16x8*)&As[(wm + i * 16 + l15) * 32 + lg * 8];
            bg[i] = *(const s16x8*)&Bs[(wn + i * 16 + l15) * 32 + lg * 8];
        }
        #pragma unroll
        for (int i = 0; i < 4; ++i)
            #pragma unroll
            for (int j = 0; j < 4; ++j)
                acc[i][j] = __builtin_amdgcn_mfma_f32_16x16x32_bf16(af[i], bg[j], acc[i][j], 0, 0, 0);
        __syncthreads();
    }

    const long cb0 = (long)z * cBS;
    #pragma unroll
    for (int j = 0; j < 4; ++j) {
        const int col = n0 + wn + j * 16 + l15;
        if (col >= N) continue;
        #pragma unroll
        for (int i = 0; i < 4; ++i) {
            #pragma unroll
            for (int r = 0; r < 4; ++r) {
                const int row = m0 + wm + i * 16 + lg * 4 + r;
                const float v = acc[i][j][r];
                const long idx = cb0 + (long)row * ldc + col;
                if (EPI == 0) {
                    Cf[idx] = v;
                } else if (EPI == 1) {
                    Cf[idx] += v;
                } else if (EPI == 2) {
                    float x = v + Cf[idx] + bias[col];
                    Cb[idx] = f2b(fmaxf(x, 0.f));
                } else if (EPI == 3) {
                    const int grow = z * M + row;
                    const float bb = biasBStride ? bias[(grow >> 10) * biasBStride + col] : bias[col];
                    float x = fmaxf(v + bb, 0.f);
                    if (mask) x *= mask[grow];
                    Cb[idx] = f2b(x);
                } else if (EPI == 4) {
                    float x = v * mask[z * M + row] * mask[z * N + col];
                    Cb[idx] = f2b(x);
                } else if (EPI == 5) {
                    Cb[idx] = f2b(v);
                } else {
                    float x = 2.f * v - b2f(prev2[idx]);
                    Cb[idx] = f2b(x);
                }
            }
        }
    }
}

// fp32 [K][N] -> bf16 [n][Kpad] transpose+convert, zero pad for k in [K,Kpad)
__global__ void cvtT_k(const float* __restrict__ src, u16* __restrict__ dst,
                       int K, int N, int Kpad, long sBS, long dBS)
{
    __shared__ float t[32][33];
    const int tx = threadIdx.x, ty = threadIdx.y;
    const int k0 = blockIdx.x * 32, n0 = blockIdx.y * 32;
    src += (long)blockIdx.z * sBS;
    dst += (long)blockIdx.z * dBS;
    #pragma unroll
    for (int rr = ty; rr < 32; rr += 8) {
        int k = k0 + rr, n = n0 + tx;
        t[rr][tx] = (k < K && n < N) ? src[(long)k * N + n] : 0.f;
    }
    __syncthreads();
    #pragma unroll
    for (int rr = ty; rr < 32; rr += 8) {
        int n = n0 + rr, k = k0 + tx;
        if (n < N && k < Kpad) dst[(long)n * Kpad + k] = f2b(t[tx][rr]);
    }
}

// bf16 [R][C] -> bf16 [C][R], batched
__global__ void tranb_k(const u16* __restrict__ src, u16* __restrict__ dst,
                        int R, int C, long sBS, long dBS)
{
    __shared__ u16 t[32][33];
    const int tx = threadIdx.x, ty = threadIdx.y;
    const int r0 = blockIdx.y * 32, c0 = blockIdx.x * 32;
    src += (long)blockIdx.z * sBS;
    dst += (long)blockIdx.z * dBS;
    #pragma unroll
    for (int rr = ty; rr < 32; rr += 8)
        t[rr][tx] = src[(long)(r0 + rr) * C + c0 + tx];
    __syncthreads();
    #pragma unroll
    for (int rr = ty; rr < 32; rr += 8)
        dst[(long)(c0 + rr) * R + r0 + tx] = t[tx][rr];
}

__global__ void cvt_k(const float* __restrict__ src, u16* __restrict__ dst, int n)
{
    for (long i = (long)(blockIdx.x * 256 + threadIdx.x) * 4; i < n; i += (long)gridDim.x * 1024) {
        float4 v = *(const float4*)&src[i];
        unsigned long long pk = (unsigned long long)f2b(v.x)
                              | ((unsigned long long)f2b(v.y) << 16)
                              | ((unsigned long long)f2b(v.z) << 32)
                              | ((unsigned long long)f2b(v.w) << 48);
        *(unsigned long long*)&dst[i] = pk;
    }
}

__global__ void mask_k(const float* __restrict__ inp, float* __restrict__ mask)
{
    const int row = blockIdx.x, tid = threadIdx.x;
    float4 v = *(const float4*)&inp[(long)row * 1024 + tid * 4];
    float s = v.x + v.y + v.z + v.w;
    __shared__ float red[256];
    red[tid] = s; __syncthreads();
    for (int o = 128; o > 0; o >>= 1) { if (tid < o) red[tid] += red[tid + o]; __syncthreads(); }
    if (tid == 0) mask[row] = (red[0] != 0.f) ? 1.f : 0.f;
}

__global__ void numel_k(const float* __restrict__ mask, float* __restrict__ numel)
{
    const int b = blockIdx.x, tid = threadIdx.x;
    float4 v = *(const float4*)&mask[b * 1024 + tid * 4];
    float s = v.x + v.y + v.z + v.w;
    __shared__ float red[256];
    red[tid] = s; __syncthreads();
    for (int o = 128; o > 0; o >>= 1) { if (tid < o) red[tid] += red[tid + o]; __syncthreads(); }
    if (tid == 0) numel[b] = red[0];
}

__global__ void colmean_k(const u16* __restrict__ fea, const float* __restrict__ numel,
                          float* __restrict__ mean)
{
    const int b = blockIdx.x, f = threadIdx.x; // 512 threads
    const u16* p = fea + (long)b * 1024 * 512 + f;
    float s = 0.f;
    for (int n = 0; n < 1024; ++n) s += b2f(p[n * 512]);
    mean[b * 512 + f] = s / numel[b];
}

__global__ void cvec_k(const float* __restrict__ mean, const float* __restrict__ Wc,
                       const float* __restrict__ bc, float* __restrict__ c)
{
    const int o = threadIdx.x; // 128
    for (int b = 0; b < 8; ++b) {
        float s = bc[o];
        const float* m = mean + b * 512;
        for (int f = 0; f < 512; ++f) s += m[f] * Wc[f * 128 + o];
        c[b * 128 + o] = fmaxf(s, 0.f);
    }
}

__global__ void cbias_k(const float* __restrict__ c, const float* __restrict__ Wa1,
                        const float* __restrict__ ba1, float* __restrict__ cb)
{
    const int b = blockIdx.x, o = threadIdx.x; // 512
    float s = ba1[o];
    const float* cc = c + b * 128;
    for (int j = 0; j < 128; ++j) s += cc[j] * Wa1[(512 + j) * 512 + o];
    cb[b * 512 + o] = s;
}

__global__ void dinv_k(const u16* __restrict__ Abf, float* __restrict__ dinv)
{
    const int row = blockIdx.x, tid = threadIdx.x;
    const u16* p = Abf + (long)row * 1024 + tid * 4;
    float s = b2f(p[0]) + b2f(p[1]) + b2f(p[2]) + b2f(p[3]);
    __shared__ float red[256];
    red[tid] = s; __syncthreads();
    for (int o = 128; o > 0; o >>= 1) { if (tid < o) red[tid] += red[tid + o]; __syncthreads(); }
    if (tid == 0) {
        float d = red[0];
        dinv[row] = d > 0.f ? rsqrtf(fmaxf(d, 1e-30f)) : 0.f;
    }
}

__global__ void lhat_k(u16* __restrict__ Abf, const float* __restrict__ dinv)
{
    const long e0 = ((long)blockIdx.x * 256 + threadIdx.x) * 4;
    const int b = (int)(e0 >> 20);
    const int i = (int)((e0 >> 10) & 1023);
    const int j = (int)(e0 & 1023);
    const float di = dinv[b * 1024 + i];
    u16* p = Abf + e0;
    #pragma unroll
    for (int t = 0; t < 4; ++t) {
        float v = -di * b2f(p[t]) * dinv[b * 1024 + j + t];
        p[t] = f2b(v);
    }
}

__global__ void gate_k(const u16* __restrict__ g2, const float* __restrict__ Wp3,
                       const float* __restrict__ bp3, const float* __restrict__ mask,
                       float* __restrict__ gate)
{
    const int row = blockIdx.x * 4 + (threadIdx.x >> 6);
    const int lane = threadIdx.x & 63;
    float v = b2f(g2[row * 64 + lane]) * Wp3[lane];
    for (int o = 32; o > 0; o >>= 1) v += __shfl_xor(v, o, 64);
    if (lane == 0)
        gate[row] = (mask[row] > 0.f) ? tanhf(v + bp3[0]) : -1e9f;
}

__global__ void pool_k(const float* __restrict__ gate, const u16* __restrict__ x2,
                       float* __restrict__ pooled)
{
    const int b = blockIdx.x, tid = threadIdx.x; // 384
    __shared__ float att[1024];
    __shared__ float wred[8];
    __shared__ float bcv[1];
    const float* g = gate + b * 1024;
    float m = -1e30f;
    for (int n = tid; n < 1024; n += 384) m = fmaxf(m, g[n]);
    for (int o = 32; o > 0; o >>= 1) m = fmaxf(m, __shfl_xor(m, o, 64));
    if ((tid & 63) == 0) wred[tid >> 6] = m;
    __syncthreads();
    if (tid == 0) { float mm = wred[0]; for (int w = 1; w < 6; ++w) mm = fmaxf(mm, wred[w]); bcv[0] = mm; }
    __syncthreads();
    const float mx = bcv[0];
    float zs = 0.f;
    for (int n = tid; n < 1024; n += 384) { float e = expf(g[n] - mx); att[n] = e; zs += e; }
    for (int o = 32; o > 0; o >>= 1) zs += __shfl_xor(zs, o, 64);
    __syncthreads();
    if ((tid & 63) == 0) wred[tid >> 6] = zs;
    __syncthreads();
    if (tid == 0) { float s = 0.f; for (int w = 0; w < 6; ++w) s += wred[w]; bcv[0] = 1.f / s; }
    __syncthreads();
    const float zi = bcv[0];
    const u16* xb = x2 + (long)b * 1024 * 384 + tid;
    float s = 0.f;
    for (int n = 0; n < 1024; ++n) s += att[n] * b2f(xb[(long)n * 384]);
    pooled[b * 384 + tid] = s * zi;
}

__global__ void final_k(const float* __restrict__ pooled, const float* __restrict__ Wm1,
                        const float* __restrict__ bm1, const float* __restrict__ Wm2,
                        const float* __restrict__ bm2, float* __restrict__ out)
{
    __shared__ float wred[4];
    const int tid = threadIdx.x; // 256
    for (int b = 0; b < 8; ++b) {
        float s = bm1[tid];
        const float* p = pooled + b * 384;
        for (int f = 0; f < 384; ++f) s += p[f] * Wm1[f * 256 + tid];
        float o = fmaxf(s, 0.f);
        float v = o * Wm2[tid];
        for (int off = 32; off > 0; off >>= 1) v += __shfl_xor(v, off, 64);
        if ((tid & 63) == 0) wred[tid >> 6] = v;
        __syncthreads();
        if (tid == 0) {
            float t = wred[0] + wred[1] + wred[2] + wred[3] + bm2[0];
            out[b] = 1.f / (1.f + expf(-t));
        }
        __syncthreads();
    }
}

// ---------------------------------------------------------------------------
// workspace layout (bytes, all 512-aligned)
// ---------------------------------------------------------------------------
constexpr size_t SZ_WF1T = 896ull * 1024 * 2;
constexpr size_t SZ_WF2T = 512ull * 800 * 2;
constexpr size_t SZ_WF3T = 512ull * 512 * 2;
constexpr size_t SZ_WA1T = 512ull * 512 * 2;
constexpr size_t SZ_WA2T = 384ull * 512 * 2;
constexpr size_t SZ_WG1T = 5ull * 512 * 512 * 2;
constexpr size_t SZ_WG2T = 5ull * 384 * 512 * 2;
constexpr size_t SZ_WP1T = 128ull * 384 * 2;
constexpr size_t SZ_WP2T = 128ull * 128 * 2;

constexpr size_t OFS_WF1T = 0;
constexpr size_t OFS_WF2T = OFS_WF1T + SZ_WF1T;
constexpr size_t OFS_WF3T = OFS_WF2T + SZ_WF2T;
constexpr size_t OFS_WA1T = OFS_WF3T + SZ_WF3T;
constexpr size_t OFS_WA2T = OFS_WA1T + SZ_WA1T;
constexpr size_t OFS_WG1T = OFS_WA2T + SZ_WA2T;
constexpr size_t OFS_WG2T = OFS_WG1T + SZ_WG1T;
constexpr size_t OFS_WP1T = OFS_WG2T + SZ_WG2T;
constexpr size_t OFS_WP2T = OFS_WP1T + SZ_WP1T;
constexpr size_t OFS_MASK = OFS_WP2T + SZ_WP2T;
constexpr size_t OFS_NUMEL = OFS_MASK + 32768;
constexpr size_t OFS_MEAN = OFS_NUMEL + 512;
constexpr size_t OFS_CVEC = OFS_MEAN + 16384;
constexpr size_t OFS_CB   = OFS_CVEC + 4096;
constexpr size_t OFS_DINV = OFS_CB + 16384;
constexpr size_t OFS_GATE = OFS_DINV + 32768;
constexpr size_t OFS_POOL = OFS_GATE + 32768;
constexpr size_t OFS_XBF  = OFS_POOL + 12288;        // 16 MiB region; later: a1, then g1/g2
constexpr size_t OFS_H1   = OFS_XBF + 16777216;      // 12.5 MiB; later: a2, then x2
constexpr size_t OFS_H2   = OFS_H1 + 13107200;       // 8 MiB; later: x1
constexpr size_t OFS_FEA  = OFS_H2 + 8388608;
constexpr size_t OFS_ABF  = OFS_FEA + 8388608;       // A, then Lhat in-place
constexpr size_t OFS_TT   = OFS_ABF + 16777216;
constexpr size_t OFS_TB1  = OFS_TT + 8388608;
constexpr size_t OFS_TB2  = OFS_TB1 + 8388608;
constexpr size_t OFS_ACC  = OFS_TB2 + 8388608;
constexpr size_t WS_TOTAL = OFS_ACC + 16777216;

extern "C" void kernel_launch(void* const* d_in, const int* in_sizes, int n_in,
                              void* d_out, int out_size, void* d_ws, size_t ws_size,
                              hipStream_t stream)
{
    const float* inp = (const float*)d_in[0];
    const float* Wf1 = (const float*)d_in[2];  const float* bf1 = (const float*)d_in[3];
    const float* Wf2 = (const float*)d_in[4];  const float* bf2 = (const float*)d_in[5];
    const float* Wf3 = (const float*)d_in[6];  const float* bf3 = (const float*)d_in[7];
    const float* Wc  = (const float*)d_in[8];  const float* bc  = (const float*)d_in[9];
    const float* Wa1 = (const float*)d_in[10]; const float* ba1 = (const float*)d_in[11];
    const float* Wa2 = (const float*)d_in[12]; const float* ba2 = (const float*)d_in[13];
    const float* Wg1 = (const float*)d_in[14]; const float* bg1 = (const float*)d_in[15];
    const float* Wg2 = (const float*)d_in[16]; const float* bg2 = (const float*)d_in[17];
    const float* Wp1 = (const float*)d_in[18]; const float* bp1 = (const float*)d_in[19];
    const float* Wp2 = (const float*)d_in[20]; const float* bp2 = (const float*)d_in[21];
    const float* Wp3 = (const float*)d_in[22]; const float* bp3 = (const float*)d_in[23];
    const float* Wm1 = (const float*)d_in[24]; const float* bm1 = (const float*)d_in[25];
    const float* Wm2 = (const float*)d_in[26]; const float* bm2 = (const float*)d_in[27];

    if (ws_size < WS_TOTAL) return;
    char* ws = (char*)d_ws;

    u16* wf1t = (u16*)(ws + OFS_WF1T);
    u16* wf2t = (u16*)(ws + OFS_WF2T);
    u16* wf3t = (u16*)(ws + OFS_WF3T);
    u16* wa1t = (u16*)(ws + OFS_WA1T);
    u16* wa2t = (u16*)(ws + OFS_WA2T);
    u16* wg1t = (u16*)(ws + OFS_WG1T);
    u16* wg2t = (u16*)(ws + OFS_WG2T);
    u16* wp1t = (u16*)(ws + OFS_WP1T);
    u16* wp2t = (u16*)(ws + OFS_WP2T);
    float* maskv  = (float*)(ws + OFS_MASK);
    float* numelv = (float*)(ws + OFS_NUMEL);
    float* meanv  = (float*)(ws + OFS_MEAN);
    float* cvecv  = (float*)(ws + OFS_CVEC);
    float* cbv    = (float*)(ws + OFS_CB);
    float* dinvv  = (float*)(ws + OFS_DINV);
    float* gatev  = (float*)(ws + OFS_GATE);
    float* pooledv= (float*)(ws + OFS_POOL);
    u16* xbf = (u16*)(ws + OFS_XBF);
    u16* a1  = (u16*)(ws + OFS_XBF);                 // xbf dead after f1
    u16* g1  = (u16*)(ws + OFS_XBF);                 // a1 dead after a2
    u16* g2  = (u16*)(ws + OFS_XBF + 2097152);
    u16* h1  = (u16*)(ws + OFS_H1);
    u16* a2  = (u16*)(ws + OFS_H1);                  // h1 dead after f2
    u16* x2  = (u16*)(ws + OFS_H1);                  // a2 dead after adjm
    u16* h2  = (u16*)(ws + OFS_H2);
    u16* x1  = (u16*)(ws + OFS_H2);                  // h2 dead after f3
    u16* fea = (u16*)(ws + OFS_FEA);
    u16* abf = (u16*)(ws + OFS_ABF);                 // A, then Lhat in-place
    u16* tt  = (u16*)(ws + OFS_TT);
    u16* tb1 = (u16*)(ws + OFS_TB1);
    u16* tb2 = (u16*)(ws + OFS_TB2);
    float* acc = (float*)(ws + OFS_ACC);

    const dim3 tblk(32, 8);

    // weight convert + transpose (fp32 [K][N] -> bf16 [N][Kpad])
    cvtT_k<<<dim3(32, 25, 1), tblk, 0, stream>>>(Wf1, wf1t, 1024, 784, 1024, 0, 0);
    cvtT_k<<<dim3(25, 16, 1), tblk, 0, stream>>>(Wf2, wf2t, 784, 512, 800, 0, 0);
    cvtT_k<<<dim3(16, 16, 1), tblk, 0, stream>>>(Wf3, wf3t, 512, 512, 512, 0, 0);
    cvtT_k<<<dim3(16, 16, 1), tblk, 0, stream>>>(Wa1, wa1t, 512, 512, 512, 0, 0);
    cvtT_k<<<dim3(16, 12, 1), tblk, 0, stream>>>(Wa2, wa2t, 512, 384, 512, 0, 0);
    cvtT_k<<<dim3(16, 16, 5), tblk, 0, stream>>>(Wg1, wg1t, 512, 512, 512, 262144, 262144);
    cvtT_k<<<dim3(16, 12, 5), tblk, 0, stream>>>(Wg2, wg2t, 512, 384, 512, 196608, 196608);
    cvtT_k<<<dim3(12, 4, 1),  tblk, 0, stream>>>(Wp1, wp1t, 384, 128, 384, 0, 0);
    cvtT_k<<<dim3(4, 2, 1),   tblk, 0, stream>>>(Wp2, wp2t, 128, 64, 128, 0, 0);

    cvt_k<<<4096, 256, 0, stream>>>(inp, xbf, 8 * 1024 * 1024);
    mask_k<<<8192, 256, 0, stream>>>(inp, maskv);
    numel_k<<<8, 256, 0, stream>>>(maskv, numelv);

    // fe_extrator
    gemm_bt<3><<<dim3(7, 64, 1), 256, 0, stream>>>(xbf, wf1t, nullptr, h1, bf1, 0, maskv, nullptr,
        8192, 784, 1024, 1024, 1024, 800, 0, 0, 0);
    gemm_bt<3><<<dim3(4, 64, 1), 256, 0, stream>>>(h1, wf2t, nullptr, h2, bf2, 0, maskv, nullptr,
        8192, 512, 800, 800, 800, 512, 0, 0, 0);
    gemm_bt<3><<<dim3(4, 64, 1), 256, 0, stream>>>(h2, wf3t, nullptr, fea, bf3, 0, maskv, nullptr,
        8192, 512, 512, 512, 512, 512, 0, 0, 0);

    // c vector + per-batch bias for adj layer 1
    colmean_k<<<8, 512, 0, stream>>>(fea, numelv, meanv);
    cvec_k<<<1, 128, 0, stream>>>(meanv, Wc, bc, cvecv);
    cbias_k<<<8, 512, 0, stream>>>(cvecv, Wa1, ba1, cbv);

    // adj net
    gemm_bt<3><<<dim3(4, 64, 1), 256, 0, stream>>>(fea, wa1t, nullptr, a1, cbv, 512, maskv, nullptr,
        8192, 512, 512, 512, 512, 512, 0, 0, 0);
    gemm_bt<3><<<dim3(3, 64, 1), 256, 0, stream>>>(a1, wa2t, nullptr, a2, ba2, 0, maskv, nullptr,
        8192, 384, 512, 512, 512, 384, 0, 0, 0);

    // adjacency A = (a2 a2^T) * pairmask, then deg -> dinv, then Lhat in-place
    gemm_bt<4><<<dim3(8, 8, 8), 256, 0, stream>>>(a2, a2, nullptr, abf, nullptr, 0, maskv, nullptr,
        1024, 1024, 384, 384, 384, 1024, 393216, 393216, 1048576);
    dinv_k<<<8192, 256, 0, stream>>>(abf, dinvv);
    lhat_k<<<8192, 256, 0, stream>>>(abf, dinvv);

    // ChebConv helper: assumes tt holds Tin^T on entry
    auto cheb = [&](const u16* Tin, const u16* WT, long wstr, int Wn, const float* bias, u16* outb) {
        dim3 gW(Wn / 128, 64, 1);
        dim3 gL(4, 8, 8);
        dim3 gT(16, 32, 8);
        gemm_bt<0><<<gW, 256, 0, stream>>>(Tin, WT, acc, nullptr, nullptr, 0, nullptr, nullptr,
            8192, Wn, 512, 512, 512, Wn, 0, 0, 0);
        gemm_bt<5><<<gL, 256, 0, stream>>>(abf, tt, nullptr, tb1, nullptr, 0, nullptr, nullptr,
            1024, 512, 1024, 1024, 1024, 512, 1048576, 524288, 524288);
        tranb_k<<<gT, tblk, 0, stream>>>(tb1, tt, 1024, 512, 524288, 524288);
        gemm_bt<1><<<gW, 256, 0, stream>>>(tb1, WT + wstr, acc, nullptr, nullptr, 0, nullptr, nullptr,
            8192, Wn, 512, 512, 512, Wn, 0, 0, 0);
        gemm_bt<6><<<gL, 256, 0, stream>>>(abf, tt, nullptr, tb2, nullptr, 0, nullptr, Tin,
            1024, 512, 1024, 1024, 1024, 512, 1048576, 524288, 524288);
        tranb_k<<<gT, tblk, 0, stream>>>(tb2, tt, 1024, 512, 524288, 524288);
        gemm_bt<1><<<gW, 256, 0, stream>>>(tb2, WT + 2 * wstr, acc, nullptr, nullptr, 0, nullptr, nullptr,
            8192, Wn, 512, 512, 512, Wn, 0, 0, 0);
        gemm_bt<6><<<gL, 256, 0, stream>>>(abf, tt, nullptr, tb1, nullptr, 0, nullptr, tb1,
            1024, 512, 1024, 1024, 1024, 512, 1048576, 524288, 524288);
        tranb_k<<<gT, tblk, 0, stream>>>(tb1, tt, 1024, 512, 524288, 524288);
        gemm_bt<1><<<gW, 256, 0, stream>>>(tb1, WT + 3 * wstr, acc, nullptr, nullptr, 0, nullptr, nullptr,
            8192, Wn, 512, 512, 512, Wn, 0, 0, 0);
        gemm_bt<6><<<gL, 256, 0, stream>>>(abf, tt, nullptr, tb2, nullptr, 0, nullptr, tb2,
            1024, 512, 1024, 1024, 1024, 512, 1048576, 524288, 524288);
        gemm_bt<2><<<gW, 256, 0, stream>>>(tb2, WT + 4 * wstr, acc, outb, bias, 0, nullptr, nullptr,
            8192, Wn, 512, 512, 512, Wn, 0, 0, 0);
    };

    tranb_k<<<dim3(16, 32, 8), tblk, 0, stream>>>(fea, tt, 1024, 512, 524288, 524288);
    cheb(fea, wg1t, 262144, 512, bg1, x1);
    tranb_k<<<dim3(16, 32, 8), tblk, 0, stream>>>(x1, tt, 1024, 512, 524288, 524288);
    cheb(x1, wg2t, 196608, 384, bg2, x2);

    // attention gate net
    gemm_bt<3><<<dim3(1, 64, 1), 256, 0, stream>>>(x2, wp1t, nullptr, g1, bp1, 0, nullptr, nullptr,
        8192, 128, 384, 384, 384, 128, 0, 0, 0);
    gemm_bt<3><<<dim3(1, 64, 1), 256, 0, stream>>>(g1, wp2t, nullptr, g2, bp2, 0, nullptr, nullptr,
        8192, 64, 128, 128, 128, 64, 0, 0, 0);
    gate_k<<<2048, 256, 0, stream>>>(g2, Wp3, bp3, maskv, gatev);
    pool_k<<<8, 384, 0, stream>>>(gatev, x2, pooledv);
    final_k<<<1, 256, 0, stream>>>(pooledv, Wm1, bm1, Wm2, bm2, (float*)d_out);
}

// Round 4
// 866.120 us; speedup vs baseline: 1.3792x; 1.3792x over previous
//
#include <hip/hip_runtime.h>
#include <hip/hip_bf16.h>

typedef unsigned short u16;
typedef float f32x4 __attribute__((ext_vector_type(4)));
typedef short s16x8 __attribute__((ext_vector_type(8)));

__device__ __forceinline__ float b2f(u16 u) {
    unsigned int x = ((unsigned int)u) << 16;
    return __builtin_bit_cast(float, x);
}
__device__ __forceinline__ u16 f2b(float f) {
    unsigned int x = __builtin_bit_cast(unsigned int, f);
    unsigned int lsb = (x >> 16) & 1u;
    x += 0x7fffu + lsb;                 // RNE; inputs are finite
    return (u16)(x >> 16);
}

#define GLOAD_LDS(g, l) __builtin_amdgcn_global_load_lds( \
    (const __attribute__((address_space(1))) void*)(g),   \
    (__attribute__((address_space(3))) void*)(l), 16, 0, 0)

// ---------------------------------------------------------------------------
// Batched GEMM: C[z,m,n] = sum_k A[z,m,k] * B[z,n,k]   (B stored [N][K])
// Tile 128xTN, BK=32, 256 threads = 4 waves, mfma_f32_16x16x32_bf16.
// Double-buffered LDS: STAGE(t+1) issued before compute(t); 1 barrier/K-step.
// EPI: 0 Cf=acc                      2 Cb=relu(acc+Cf+bias)
//      3 Cb=relu(acc+bias)*mask      4 Cb=acc*mask[row]*mask[col]
//      5 Cb=acc                      6 Cb=2*acc - prev2
// ---------------------------------------------------------------------------
template<int EPI, int TN>
__global__ __launch_bounds__(256)
void gemm_bt(const u16* __restrict__ A, const u16* __restrict__ B,
             float* __restrict__ Cf, u16* __restrict__ Cb,
             const float* __restrict__ bias, int biasBStride,
             const float* __restrict__ mask,
             const u16* __restrict__ prev2, int ldp, long pBS,
             int M, int N, int K, int lda, int ldb, int ldc,
             long aBS, long bBS, long cBS)
{
    constexpr int NJ = (TN == 128) ? 4 : 2;
    __shared__ u16 As[2][128 * 32];
    __shared__ u16 Bs[2][TN * 32];
    const int tid  = threadIdx.x;
    const int lane = tid & 63;
    const int z    = blockIdx.z;
    const int m0   = blockIdx.y * 128;
    const int n0   = blockIdx.x * TN;
    const int wm   = ((tid >> 7) & 1) * 64;
    const int wn   = ((tid >> 6) & 1) * (TN / 2);
    const int l15  = lane & 15;
    const int lg   = lane >> 4;
    const u16* Ab = A + (long)z * aBS;
    const u16* Bb = B + (long)z * bBS;

    f32x4 acc[4][NJ] = {};
    const int nt = K >> 5;

    auto stage = [&](int s, int t) {
        const int u0 = tid, u1 = tid + 256;
        GLOAD_LDS(Ab + (long)(m0 + (u0 >> 2)) * lda + t * 32 + (u0 & 3) * 8, &As[s][u0 * 8]);
        GLOAD_LDS(Ab + (long)(m0 + (u1 >> 2)) * lda + t * 32 + (u1 & 3) * 8, &As[s][u1 * 8]);
        GLOAD_LDS(Bb + (long)(n0 + (u0 >> 2)) * ldb + t * 32 + (u0 & 3) * 8, &Bs[s][u0 * 8]);
        if (TN == 128)
            GLOAD_LDS(Bb + (long)(n0 + (u1 >> 2)) * ldb + t * 32 + (u1 & 3) * 8, &Bs[s][u1 * 8]);
    };

    stage(0, 0);
    __syncthreads();
    for (int t = 0; t < nt; ++t) {
        const int cur = t & 1;
        if (t + 1 < nt) stage(cur ^ 1, t + 1);   // next-tile loads in flight
        s16x8 af[4], bg[NJ];
        #pragma unroll
        for (int i = 0; i < 4; ++i)
            af[i] = *(const s16x8*)&As[cur][(wm + i * 16 + l15) * 32 + lg * 8];
        #pragma unroll
        for (int j = 0; j < NJ; ++j)
            bg[j] = *(const s16x8*)&Bs[cur][(wn + j * 16 + l15) * 32 + lg * 8];
        #pragma unroll
        for (int i = 0; i < 4; ++i)
            #pragma unroll
            for (int j = 0; j < NJ; ++j)
                acc[i][j] = __builtin_amdgcn_mfma_f32_16x16x32_bf16(af[i], bg[j], acc[i][j], 0, 0, 0);
        __syncthreads();                          // drains vmcnt: tile t+1 ready
    }

    const long cb0 = (long)z * cBS;
    #pragma unroll
    for (int j = 0; j < NJ; ++j) {
        const int col = n0 + wn + j * 16 + l15;
        if (col >= N) continue;
        #pragma unroll
        for (int i = 0; i < 4; ++i) {
            #pragma unroll
            for (int r = 0; r < 4; ++r) {
                const int row = m0 + wm + i * 16 + lg * 4 + r;
                const float v = acc[i][j][r];
                const long idx = cb0 + (long)row * ldc + col;
                if (EPI == 0) {
                    Cf[idx] = v;
                } else if (EPI == 2) {
                    float x = v + Cf[idx] + bias[col];
                    Cb[idx] = f2b(fmaxf(x, 0.f));
                } else if (EPI == 3) {
                    const int grow = z * M + row;
                    const float bb = biasBStride ? bias[(grow >> 10) * biasBStride + col] : bias[col];
                    float x = fmaxf(v + bb, 0.f);
                    if (mask) x *= mask[grow];
                    Cb[idx] = f2b(x);
                } else if (EPI == 4) {
                    float x = v * mask[z * M + row] * mask[z * N + col];
                    Cb[idx] = f2b(x);
                } else if (EPI == 5) {
                    Cb[idx] = f2b(v);
                } else {
                    float x = 2.f * v - b2f(prev2[(long)z * pBS + (long)row * ldp + col]);
                    Cb[idx] = f2b(x);
                }
            }
        }
    }
}

// fp32 [K][N] -> bf16 [n][ldD] transpose+convert, zero pad for k in [K,Kpad)
__global__ void cvtT_k(const float* __restrict__ src, u16* __restrict__ dst,
                       int K, int N, int Kpad, int ldD, long sBS, long dBS)
{
    __shared__ float t[32][33];
    const int tx = threadIdx.x, ty = threadIdx.y;
    const int k0 = blockIdx.x * 32, n0 = blockIdx.y * 32;
    src += (long)blockIdx.z * sBS;
    dst += (long)blockIdx.z * dBS;
    #pragma unroll
    for (int rr = ty; rr < 32; rr += 8) {
        int k = k0 + rr, n = n0 + tx;
        t[rr][tx] = (k < K && n < N) ? src[(long)k * N + n] : 0.f;
    }
    __syncthreads();
    #pragma unroll
    for (int rr = ty; rr < 32; rr += 8) {
        int n = n0 + rr, k = k0 + tx;
        if (n < N && k < Kpad) dst[(long)n * ldD + k] = f2b(t[tx][rr]);
    }
}

// bf16 [R][C] (row stride lds_) -> bf16 [C][R] (row stride ldd_), batched
__global__ void tranb_k(const u16* __restrict__ src, u16* __restrict__ dst,
                        int lds_, int ldd_, long sBS, long dBS)
{
    __shared__ u16 t[32][33];
    const int tx = threadIdx.x, ty = threadIdx.y;
    const int r0 = blockIdx.y * 32, c0 = blockIdx.x * 32;
    src += (long)blockIdx.z * sBS;
    dst += (long)blockIdx.z * dBS;
    #pragma unroll
    for (int rr = ty; rr < 32; rr += 8)
        t[rr][tx] = src[(long)(r0 + rr) * lds_ + c0 + tx];
    __syncthreads();
    #pragma unroll
    for (int rr = ty; rr < 32; rr += 8)
        dst[(long)(c0 + rr) * ldd_ + r0 + tx] = t[tx][rr];
}

__global__ void cvt_k(const float* __restrict__ src, u16* __restrict__ dst, int n)
{
    for (long i = (long)(blockIdx.x * 256 + threadIdx.x) * 4; i < n; i += (long)gridDim.x * 1024) {
        float4 v = *(const float4*)&src[i];
        unsigned long long pk = (unsigned long long)f2b(v.x)
                              | ((unsigned long long)f2b(v.y) << 16)
                              | ((unsigned long long)f2b(v.z) << 32)
                              | ((unsigned long long)f2b(v.w) << 48);
        *(unsigned long long*)&dst[i] = pk;
    }
}

__global__ void zero_k(float* __restrict__ p, int n)
{
    const int i = blockIdx.x * 256 + threadIdx.x;
    if (i < n) p[i] = 0.f;
}

__global__ void mask_k(const float* __restrict__ inp, float* __restrict__ mask)
{
    const int row = blockIdx.x, tid = threadIdx.x;
    float4 v = *(const float4*)&inp[(long)row * 1024 + tid * 4];
    float s = v.x + v.y + v.z + v.w;
    __shared__ float red[256];
    red[tid] = s; __syncthreads();
    for (int o = 128; o > 0; o >>= 1) { if (tid < o) red[tid] += red[tid + o]; __syncthreads(); }
    if (tid == 0) mask[row] = (red[0] != 0.f) ? 1.f : 0.f;
}

__global__ void numel_k(const float* __restrict__ mask, float* __restrict__ numel)
{
    const int b = blockIdx.x, tid = threadIdx.x;
    float4 v = *(const float4*)&mask[b * 1024 + tid * 4];
    float s = v.x + v.y + v.z + v.w;
    __shared__ float red[256];
    red[tid] = s; __syncthreads();
    for (int o = 128; o > 0; o >>= 1) { if (tid < o) red[tid] += red[tid + o]; __syncthreads(); }
    if (tid == 0) numel[b] = red[0];
}

// partial column sums of fea into mean (pre-zeroed), 64 blocks
__global__ void colmean_k(const u16* __restrict__ fea, float* __restrict__ mean)
{
    const int b = blockIdx.y, ch = blockIdx.x, f = threadIdx.x;   // 512
    const u16* p = fea + (long)b * 1024 * 512 + (long)ch * 128 * 512 + f;
    float s = 0.f;
    for (int n = 0; n < 128; ++n) s += b2f(p[n * 512]);
    atomicAdd(&mean[b * 512 + f], s);
}

__global__ void cvec_k(const float* __restrict__ mean, const float* __restrict__ numel,
                       const float* __restrict__ Wc, const float* __restrict__ bc,
                       float* __restrict__ c)
{
    const int b = blockIdx.x, tid = threadIdx.x;  // 512
    const int o = tid & 127, q = tid >> 7;
    const float* m = mean + b * 512;
    float s = 0.f;
    for (int f = q * 128; f < q * 128 + 128; ++f) s += m[f] * Wc[f * 128 + o];
    __shared__ float red[512];
    red[tid] = s; __syncthreads();
    if (tid < 256) red[tid] += red[tid + 256];
    __syncthreads();
    if (tid < 128) {
        float tot = red[tid] + red[tid + 128];
        c[b * 128 + tid] = fmaxf(tot / numel[b] + bc[tid], 0.f);
    }
}

__global__ void cbias_k(const float* __restrict__ c, const float* __restrict__ Wa1,
                        const float* __restrict__ ba1, float* __restrict__ cb)
{
    const int b = blockIdx.x, o = threadIdx.x; // 512
    float s = ba1[o];
    const float* cc = c + b * 128;
    for (int j = 0; j < 128; ++j) s += cc[j] * Wa1[(512 + j) * 512 + o];
    cb[b * 512 + o] = s;
}

__global__ void dinv_k(const u16* __restrict__ Abf, float* __restrict__ dinv)
{
    const int row = blockIdx.x, tid = threadIdx.x;
    const u16* p = Abf + (long)row * 1024 + tid * 4;
    float s = b2f(p[0]) + b2f(p[1]) + b2f(p[2]) + b2f(p[3]);
    __shared__ float red[256];
    red[tid] = s; __syncthreads();
    for (int o = 128; o > 0; o >>= 1) { if (tid < o) red[tid] += red[tid + o]; __syncthreads(); }
    if (tid == 0) {
        float d = red[0];
        dinv[row] = d > 0.f ? rsqrtf(fmaxf(d, 1e-30f)) : 0.f;
    }
}

__global__ void lhat_k(u16* __restrict__ Abf, const float* __restrict__ dinv)
{
    const long e0 = ((long)blockIdx.x * 256 + threadIdx.x) * 4;
    const int b = (int)(e0 >> 20);
    const int i = (int)((e0 >> 10) & 1023);
    const int j = (int)(e0 & 1023);
    const float di = dinv[b * 1024 + i];
    u16* p = Abf + e0;
    #pragma unroll
    for (int t = 0; t < 4; ++t) {
        float v = -di * b2f(p[t]) * dinv[b * 1024 + j + t];
        p[t] = f2b(v);
    }
}

__global__ void gate_k(const u16* __restrict__ g2, const float* __restrict__ Wp3,
                       const float* __restrict__ bp3, const float* __restrict__ mask,
                       float* __restrict__ gate)
{
    const int row = blockIdx.x * 4 + (threadIdx.x >> 6);
    const int lane = threadIdx.x & 63;
    float v = b2f(g2[row * 64 + lane]) * Wp3[lane];
    for (int o = 32; o > 0; o >>= 1) v += __shfl_xor(v, o, 64);
    if (lane == 0)
        gate[row] = (mask[row] > 0.f) ? tanhf(v + bp3[0]) : -1e9f;
}

// per-batch softmax over 1024 gates -> att
__global__ void attw_k(const float* __restrict__ gate, float* __restrict__ att)
{
    const int b = blockIdx.x, tid = threadIdx.x;  // 256
    const float* g = gate + b * 1024;
    float4 v = *(const float4*)&g[tid * 4];
    __shared__ float red[256];
    red[tid] = fmaxf(fmaxf(v.x, v.y), fmaxf(v.z, v.w));
    __syncthreads();
    for (int o = 128; o > 0; o >>= 1) { if (tid < o) red[tid] = fmaxf(red[tid], red[tid + o]); __syncthreads(); }
    const float mx = red[0];
    __syncthreads();
    float e0 = expf(v.x - mx), e1 = expf(v.y - mx), e2 = expf(v.z - mx), e3 = expf(v.w - mx);
    red[tid] = e0 + e1 + e2 + e3;
    __syncthreads();
    for (int o = 128; o > 0; o >>= 1) { if (tid < o) red[tid] += red[tid + o]; __syncthreads(); }
    const float zi = 1.f / red[0];
    float4 w = { e0 * zi, e1 * zi, e2 * zi, e3 * zi };
    *(float4*)&att[b * 1024 + tid * 4] = w;
}

// partial weighted sums into pooled (pre-zeroed), 64 blocks
__global__ void wsum_k(const float* __restrict__ att, const u16* __restrict__ x2,
                       float* __restrict__ pooled)
{
    const int b = blockIdx.y, ch = blockIdx.x, o = threadIdx.x;  // 384
    const u16* xb = x2 + (long)b * 1024 * 384 + (long)ch * 128 * 384 + o;
    const float* ab = att + b * 1024 + ch * 128;
    float s = 0.f;
    for (int n = 0; n < 128; ++n) s += ab[n] * b2f(xb[n * 384]);
    atomicAdd(&pooled[b * 384 + o], s);
}

__global__ void final_k(const float* __restrict__ pooled, const float* __restrict__ Wm1,
                        const float* __restrict__ bm1, const float* __restrict__ Wm2,
                        const float* __restrict__ bm2, float* __restrict__ out)
{
    __shared__ float wred[4];
    const int tid = threadIdx.x; // 256
    for (int b = 0; b < 8; ++b) {
        float s = bm1[tid];
        const float* p = pooled + b * 384;
        for (int f = 0; f < 384; ++f) s += p[f] * Wm1[f * 256 + tid];
        float o = fmaxf(s, 0.f);
        float v = o * Wm2[tid];
        for (int off = 32; off > 0; off >>= 1) v += __shfl_xor(v, off, 64);
        if ((tid & 63) == 0) wred[tid >> 6] = v;
        __syncthreads();
        if (tid == 0) {
            float t = wred[0] + wred[1] + wred[2] + wred[3] + bm2[0];
            out[b] = 1.f / (1.f + expf(-t));
        }
        __syncthreads();
    }
}

// ---------------------------------------------------------------------------
// workspace layout
// ---------------------------------------------------------------------------
constexpr size_t OFS_WF1T = 0;                               // 832x1024 bf16
constexpr size_t OFS_WF2T = OFS_WF1T + 832ull * 1024 * 2;    // 512x800
constexpr size_t OFS_WF3T = OFS_WF2T + 512ull * 800 * 2;     // 512x512
constexpr size_t OFS_WA1T = OFS_WF3T + 512ull * 512 * 2;
constexpr size_t OFS_WA2T = OFS_WA1T + 512ull * 512 * 2;     // 384x512
constexpr size_t OFS_WG1T0 = OFS_WA2T + 384ull * 512 * 2;    // 512x512
constexpr size_t OFS_WG1C  = OFS_WG1T0 + 512ull * 512 * 2;   // 512x2048
constexpr size_t OFS_WG2T0 = OFS_WG1C + 512ull * 2048 * 2;   // 384x512
constexpr size_t OFS_WG2C  = OFS_WG2T0 + 384ull * 512 * 2;   // 384x2048
constexpr size_t OFS_WP1T  = OFS_WG2C + 384ull * 2048 * 2;   // 128x384
constexpr size_t OFS_WP2T  = OFS_WP1T + 128ull * 384 * 2;    // 64x128
constexpr size_t OFS_MASK  = OFS_WP2T + 64ull * 128 * 2;
constexpr size_t OFS_NUMEL = OFS_MASK + 32768;
constexpr size_t OFS_MEAN  = OFS_NUMEL + 512;
constexpr size_t OFS_CVEC  = OFS_MEAN + 16384;
constexpr size_t OFS_CB    = OFS_CVEC + 4096;
constexpr size_t OFS_DINV  = OFS_CB + 16384;
constexpr size_t OFS_GATE  = OFS_DINV + 32768;
constexpr size_t OFS_ATT   = OFS_GATE + 32768;
constexpr size_t OFS_POOL  = OFS_ATT + 32768;
constexpr size_t OFS_RA    = OFS_POOL + 16384;               // 16 MiB: xbf | a1,a2 | facc
constexpr size_t OFS_RB    = OFS_RA + 16777216;              // 12.5 MiB: h1 | tt
constexpr size_t OFS_RC    = OFS_RB + 13107200;              // 8 MiB: h2 | x1 | g1,g2
constexpr size_t OFS_RD    = OFS_RC + 8388608;               // 8 MiB: fea | x2
constexpr size_t OFS_RE    = OFS_RD + 8388608;               // 16 MiB: abf (Lhat)
constexpr size_t OFS_RF    = OFS_RE + 16777216;              // 32 MiB: Tcat (T1..T4)
constexpr size_t WS_TOTAL  = OFS_RF + 33554432;              // ~100.9 MiB

extern "C" void kernel_launch(void* const* d_in, const int* in_sizes, int n_in,
                              void* d_out, int out_size, void* d_ws, size_t ws_size,
                              hipStream_t stream)
{
    const float* inp = (const float*)d_in[0];
    const float* Wf1 = (const float*)d_in[2];  const float* bf1 = (const float*)d_in[3];
    const float* Wf2 = (const float*)d_in[4];  const float* bf2 = (const float*)d_in[5];
    const float* Wf3 = (const float*)d_in[6];  const float* bf3 = (const float*)d_in[7];
    const float* Wc  = (const float*)d_in[8];  const float* bc  = (const float*)d_in[9];
    const float* Wa1 = (const float*)d_in[10]; const float* ba1 = (const float*)d_in[11];
    const float* Wa2 = (const float*)d_in[12]; const float* ba2 = (const float*)d_in[13];
    const float* Wg1 = (const float*)d_in[14]; const float* bg1 = (const float*)d_in[15];
    const float* Wg2 = (const float*)d_in[16]; const float* bg2 = (const float*)d_in[17];
    const float* Wp1 = (const float*)d_in[18]; const float* bp1 = (const float*)d_in[19];
    const float* Wp2 = (const float*)d_in[20]; const float* bp2 = (const float*)d_in[21];
    const float* Wp3 = (const float*)d_in[22]; const float* bp3 = (const float*)d_in[23];
    const float* Wm1 = (const float*)d_in[24]; const float* bm1 = (const float*)d_in[25];
    const float* Wm2 = (const float*)d_in[26]; const float* bm2 = (const float*)d_in[27];

    if (ws_size < WS_TOTAL) return;
    char* ws = (char*)d_ws;

    u16* wf1t  = (u16*)(ws + OFS_WF1T);
    u16* wf2t  = (u16*)(ws + OFS_WF2T);
    u16* wf3t  = (u16*)(ws + OFS_WF3T);
    u16* wa1t  = (u16*)(ws + OFS_WA1T);
    u16* wa2t  = (u16*)(ws + OFS_WA2T);
    u16* wg1t0 = (u16*)(ws + OFS_WG1T0);
    u16* wg1c  = (u16*)(ws + OFS_WG1C);
    u16* wg2t0 = (u16*)(ws + OFS_WG2T0);
    u16* wg2c  = (u16*)(ws + OFS_WG2C);
    u16* wp1t  = (u16*)(ws + OFS_WP1T);
    u16* wp2t  = (u16*)(ws + OFS_WP2T);
    float* maskv   = (float*)(ws + OFS_MASK);
    float* numelv  = (float*)(ws + OFS_NUMEL);
    float* meanv   = (float*)(ws + OFS_MEAN);
    float* cvecv   = (float*)(ws + OFS_CVEC);
    float* cbv     = (float*)(ws + OFS_CB);
    float* dinvv   = (float*)(ws + OFS_DINV);
    float* gatev   = (float*)(ws + OFS_GATE);
    float* attv    = (float*)(ws + OFS_ATT);
    float* pooledv = (float*)(ws + OFS_POOL);

    u16*   xbf  = (u16*)(ws + OFS_RA);
    u16*   a1b  = (u16*)(ws + OFS_RA);                 // after f1
    u16*   a2b  = (u16*)(ws + OFS_RA + 8388608);
    float* facc = (float*)(ws + OFS_RA);               // after adjm
    u16*   h1   = (u16*)(ws + OFS_RB);
    u16*   tt   = (u16*)(ws + OFS_RB);                 // after f2
    u16*   h2   = (u16*)(ws + OFS_RC);
    u16*   x1   = (u16*)(ws + OFS_RC);                 // after f3
    u16*   g1   = (u16*)(ws + OFS_RC);                 // after cheb2
    u16*   g2   = (u16*)(ws + OFS_RC + 2097152);
    u16*   fea  = (u16*)(ws + OFS_RD);
    u16*   x2   = (u16*)(ws + OFS_RD);                 // after cheb1
    u16*   abf  = (u16*)(ws + OFS_RE);
    u16*   tcat = (u16*)(ws + OFS_RF);                 // [8192][2048] = T1..T4

    const dim3 tblk(32, 8);

    // weights: fp32 [K][N] -> bf16 [N][ld] (B^T layout for gemm_bt)
    cvtT_k<<<dim3(32, 25, 1), tblk, 0, stream>>>(Wf1, wf1t, 1024, 784, 1024, 1024, 0, 0);
    cvtT_k<<<dim3(25, 16, 1), tblk, 0, stream>>>(Wf2, wf2t, 784, 512, 800, 800, 0, 0);
    cvtT_k<<<dim3(16, 16, 1), tblk, 0, stream>>>(Wf3, wf3t, 512, 512, 512, 512, 0, 0);
    cvtT_k<<<dim3(16, 16, 1), tblk, 0, stream>>>(Wa1, wa1t, 512, 512, 512, 512, 0, 0);
    cvtT_k<<<dim3(16, 12, 1), tblk, 0, stream>>>(Wa2, wa2t, 512, 384, 512, 512, 0, 0);
    cvtT_k<<<dim3(16, 16, 1), tblk, 0, stream>>>(Wg1, wg1t0, 512, 512, 512, 512, 0, 0);
    cvtT_k<<<dim3(16, 16, 4), tblk, 0, stream>>>(Wg1 + 262144, wg1c, 512, 512, 512, 2048, 262144, 512);
    cvtT_k<<<dim3(16, 12, 1), tblk, 0, stream>>>(Wg2, wg2t0, 512, 384, 512, 512, 0, 0);
    cvtT_k<<<dim3(16, 12, 4), tblk, 0, stream>>>(Wg2 + 196608, wg2c, 512, 384, 512, 2048, 196608, 512);
    cvtT_k<<<dim3(12, 4, 1),  tblk, 0, stream>>>(Wp1, wp1t, 384, 128, 384, 384, 0, 0);
    cvtT_k<<<dim3(4, 2, 1),   tblk, 0, stream>>>(Wp2, wp2t, 128, 64, 128, 128, 0, 0);

    cvt_k<<<4096, 256, 0, stream>>>(inp, xbf, 8 * 1024 * 1024);
    mask_k<<<8192, 256, 0, stream>>>(inp, maskv);
    numel_k<<<8, 256, 0, stream>>>(maskv, numelv);

    // fe_extrator
    gemm_bt<3, 64><<<dim3(13, 64, 1), 256, 0, stream>>>(xbf, wf1t, nullptr, h1, bf1, 0, maskv,
        nullptr, 0, 0, 8192, 784, 1024, 1024, 1024, 800, 0, 0, 0);
    gemm_bt<3, 64><<<dim3(8, 64, 1), 256, 0, stream>>>(h1, wf2t, nullptr, h2, bf2, 0, maskv,
        nullptr, 0, 0, 8192, 512, 800, 800, 800, 512, 0, 0, 0);
    gemm_bt<3, 64><<<dim3(8, 64, 1), 256, 0, stream>>>(h2, wf3t, nullptr, fea, bf3, 0, maskv,
        nullptr, 0, 0, 8192, 512, 512, 512, 512, 512, 0, 0, 0);

    // c vector + per-batch bias for adj layer 1
    zero_k<<<16, 256, 0, stream>>>(meanv, 8 * 512);
    colmean_k<<<dim3(8, 8), 512, 0, stream>>>(fea, meanv);
    cvec_k<<<8, 512, 0, stream>>>(meanv, numelv, Wc, bc, cvecv);
    cbias_k<<<8, 512, 0, stream>>>(cvecv, Wa1, ba1, cbv);

    // adj net
    gemm_bt<3, 64><<<dim3(8, 64, 1), 256, 0, stream>>>(fea, wa1t, nullptr, a1b, cbv, 512, maskv,
        nullptr, 0, 0, 8192, 512, 512, 512, 512, 512, 0, 0, 0);
    gemm_bt<3, 64><<<dim3(6, 64, 1), 256, 0, stream>>>(a1b, wa2t, nullptr, a2b, ba2, 0, maskv,
        nullptr, 0, 0, 8192, 384, 512, 512, 512, 384, 0, 0, 0);

    // adjacency, degree, Lhat (in place)
    gemm_bt<4, 64><<<dim3(16, 8, 8), 256, 0, stream>>>(a2b, a2b, nullptr, abf, nullptr, 0, maskv,
        nullptr, 0, 0, 1024, 1024, 384, 384, 384, 1024, 393216, 393216, 1048576);
    dinv_k<<<8192, 256, 0, stream>>>(abf, dinvv);
    lhat_k<<<8192, 256, 0, stream>>>(abf, dinvv);

    // ChebConv: T0 separate, T1..T4 K-concat in tcat; out = T0@W0 + Tcat@Wcat + b
    auto cheb = [&](const u16* T0, const u16* W0, const u16* Wcat, int Wn,
                    const float* bias, u16* outb, float* fa) {
        const dim3 gL(8, 8, 8);
        const dim3 gTf(16, 32, 8);
        // tt = T0^T
        tranb_k<<<gTf, tblk, 0, stream>>>(T0, tt, 512, 1024, 524288, 524288);
        // T1 = Lhat @ T0
        gemm_bt<5, 64><<<gL, 256, 0, stream>>>(abf, tt, nullptr, tcat, nullptr, 0, nullptr,
            nullptr, 0, 0, 1024, 512, 1024, 1024, 1024, 2048, 1048576, 524288, 2097152);
        tranb_k<<<gTf, tblk, 0, stream>>>(tcat, tt, 2048, 1024, 2097152, 524288);
        // T2 = 2 Lhat T1 - T0
        gemm_bt<6, 64><<<gL, 256, 0, stream>>>(abf, tt, nullptr, tcat + 512, nullptr, 0, nullptr,
            T0, 512, 524288, 1024, 512, 1024, 1024, 1024, 2048, 1048576, 524288, 2097152);
        tranb_k<<<gTf, tblk, 0, stream>>>(tcat + 512, tt, 2048, 1024, 2097152, 524288);
        // T3 = 2 Lhat T2 - T1
        gemm_bt<6, 64><<<gL, 256, 0, stream>>>(abf, tt, nullptr, tcat + 1024, nullptr, 0, nullptr,
            tcat, 2048, 2097152, 1024, 512, 1024, 1024, 1024, 2048, 1048576, 524288, 2097152);
        tranb_k<<<gTf, tblk, 0, stream>>>(tcat + 1024, tt, 2048, 1024, 2097152, 524288);
        // T4 = 2 Lhat T3 - T2
        gemm_bt<6, 64><<<gL, 256, 0, stream>>>(abf, tt, nullptr, tcat + 1536, nullptr, 0, nullptr,
            tcat + 512, 2048, 2097152, 1024, 512, 1024, 1024, 1024, 2048, 1048576, 524288, 2097152);
        // facc = T0 @ W0 ; out = relu(facc + Tcat @ Wcat + bias)
        gemm_bt<0, 64><<<dim3(Wn / 64, 64, 1), 256, 0, stream>>>(T0, W0, fa, nullptr, nullptr, 0,
            nullptr, nullptr, 0, 0, 8192, Wn, 512, 512, 512, Wn, 0, 0, 0);
        gemm_bt<2, 64><<<dim3(Wn / 64, 64, 1), 256, 0, stream>>>(tcat, Wcat, fa, outb, bias, 0,
            nullptr, nullptr, 0, 0, 8192, Wn, 2048, 2048, 2048, Wn, 0, 0, 0);
    };

    cheb(fea, wg1t0, wg1c, 512, bg1, x1, facc);
    cheb(x1,  wg2t0, wg2c, 384, bg2, x2, facc);

    // attention gate net + pooling
    gemm_bt<3, 64><<<dim3(2, 64, 1), 256, 0, stream>>>(x2, wp1t, nullptr, g1, bp1, 0, nullptr,
        nullptr, 0, 0, 8192, 128, 384, 384, 384, 128, 0, 0, 0);
    gemm_bt<3, 64><<<dim3(1, 64, 1), 256, 0, stream>>>(g1, wp2t, nullptr, g2, bp2, 0, nullptr,
        nullptr, 0, 0, 8192, 64, 128, 128, 128, 64, 0, 0, 0);
    gate_k<<<2048, 256, 0, stream>>>(g2, Wp3, bp3, maskv, gatev);
    attw_k<<<8, 256, 0, stream>>>(gatev, attv);
    zero_k<<<12, 256, 0, stream>>>(pooledv, 8 * 384);
    wsum_k<<<dim3(8, 8), 384, 0, stream>>>(attv, x2, pooledv);
    final_k<<<1, 256, 0, stream>>>(pooledv, Wm1, bm1, Wm2, bm2, (float*)d_out);
}